// Round 15
// baseline (237.588 us; speedup 1.0000x reference)
//
#include <hip/hip_runtime.h>
#include <cstdint>
#include <cstddef>

// ---------------- problem constants (from setup_inputs) ----------------
constexpr int Nn   = 50000;            // nodes
constexpr int Ee   = 800000;           // edges (without self loops)
constexpr int ETot = Ee + Nn;          // 850000 with self loops
constexpr int H1   = 8;                // heads layer 1
constexpr int C1h  = 32;               // channels/head layer 1
constexpr int HC1  = 256;              // H1*C1h
constexpr int C2   = 40;               // classes (layer 2, 1 head)
constexpr int S2   = 64;               // padded h2 row stride (halfs) = 128 B
constexpr float SLOPE = 0.2f;          // leaky_relu negative slope
constexpr int NB_SCAN = (Nn + 255) / 256;   // 196 scan blocks

typedef _Float16 f16x8 __attribute__((ext_vector_type(8)));  // 8 fp16 (4 VGPRs)
typedef __attribute__((ext_vector_type(4))) float f32x4;     // MFMA accumulator

__device__ __forceinline__ ushort f2h(float f) {             // RNE f32->fp16
    _Float16 h = (_Float16)f;
    ushort u; __builtin_memcpy(&u, &h, 2);
    return u;
}
__device__ __forceinline__ float h2f(ushort u) {
    _Float16 h; __builtin_memcpy(&h, &u, 2);
    return (float)h;
}

// async global->LDS, 16 B per lane; LDS dest = wave-uniform base + lane*16
__device__ __forceinline__ void gload16(const void* g, void* lds) {
    typedef const __attribute__((address_space(1))) unsigned int GU;
    typedef __attribute__((address_space(3))) unsigned int LU;
    __builtin_amdgcn_global_load_lds((GU*)g, (LU*)lds, 16, 0, 0);
}

// ====== merged prep: W1 pack fp16 | W2 pack fp16 | dst hist =====
// W1 -> WT2[((kb)*256+col)*8 + kr], kb in [0,32).  W2 likewise with 48 cols.
__global__ void k_prep(const float* __restrict__ w1, ushort* __restrict__ WT2,
                       const float* __restrict__ w2, ushort* __restrict__ WT2b,
                       const int* __restrict__ dstA, int* __restrict__ counts) {
    int t = blockIdx.x * blockDim.x + threadIdx.x;
    if (t < ETot) {
        int d = (t < Ee) ? dstA[t] : t - Ee;
        atomicAdd(&counts[d], 1);
    }
    if (t < 256 * 256) {
        int k = t >> 8, col = t & 255;
        float w = w1[(size_t)k * 256 + col];
        int kb = k >> 3, kr = k & 7;
        WT2[((size_t)kb * 256 + col) * 8 + kr] = f2h(w);
    }
    if (t < 256 * 48) {
        int k = t / 48, col = t % 48;
        float w = (col < C2) ? w2[(size_t)k * C2 + col] : 0.f;
        int kb = k >> 3, kr = k & 7;
        WT2b[((size_t)kb * 48 + col) * 8 + kr] = f2h(w);
    }
}

// ================= CSR build (scan -> merged top+finalize -> scatter) ========
__global__ __launch_bounds__(256) void k_scan_block(const int* __restrict__ counts,
                                                    int* __restrict__ exsc,
                                                    int* __restrict__ bsum) {
    __shared__ int sm[256];
    int i = blockIdx.x * 256 + threadIdx.x;
    int v = (i < Nn) ? counts[i] : 0;
    sm[threadIdx.x] = v;
    __syncthreads();
#pragma unroll
    for (int off = 1; off < 256; off <<= 1) {
        int t = (threadIdx.x >= off) ? sm[threadIdx.x - off] : 0;
        __syncthreads();
        sm[threadIdx.x] += t;
        __syncthreads();
    }
    if (i < Nn) exsc[i] = sm[threadIdx.x] - v;
    if (threadIdx.x == 255) bsum[blockIdx.x] = sm[255];
}

__global__ __launch_bounds__(256) void k_finalize2(const int* __restrict__ exsc,
                                                   const int* __restrict__ bsum,
                                                   int* __restrict__ row_off,
                                                   int* __restrict__ cursor) {
    __shared__ int sm[256];
    int t = threadIdx.x;
    int v = (t < NB_SCAN) ? bsum[t] : 0;
    sm[t] = v;
    __syncthreads();
#pragma unroll
    for (int off = 1; off < 256; off <<= 1) {
        int x = (t >= off) ? sm[t - off] : 0;
        __syncthreads();
        sm[t] += x;
        __syncthreads();
    }
    int i = blockIdx.x * 256 + t;
    if (i < Nn) {
        int r = exsc[i] + sm[blockIdx.x] - bsum[blockIdx.x];  // exclusive boff
        row_off[i] = r;
        cursor[i] = r;
    }
    if (i == 0) row_off[Nn] = ETot;
}

__global__ void k_scatter(const int* __restrict__ srcA, const int* __restrict__ dstA,
                          int* __restrict__ cursor, int* __restrict__ csr_src) {
    int e = blockIdx.x * blockDim.x + threadIdx.x;
    if (e >= ETot) return;
    int s, d;
    if (e < Ee) { s = srcA[e]; d = dstA[e]; } else { s = e - Ee; d = s; }
    int pos = atomicAdd(&cursor[d], 1);
    csr_src[pos] = s;
}

// ========== GEMM1 (MFMA fp16): [M,256]x[256,256], BK=64 (2 chunks/barrier) ===
// 64x256 tile, 4 waves (wave w = col block, acc[4][4]).  A: reg-stage f32 ->
// fp16 -> LDS dbuf (8 KB/buf); 4 K-steps, 32 MFMA/wave/step, 4 barriers.
// B fragments direct from L2-resident packed WT2 (131 KB). Fused alpha epilogue.
__global__ __launch_bounds__(256, 3) void k_gemm1_mfma(const float* __restrict__ x,
                                                       const ushort* __restrict__ WT2,
                                                       ushort* __restrict__ h1b,
                                                       const float* __restrict__ a_s,
                                                       const float* __restrict__ a_d,
                                                       float* __restrict__ asrc1,
                                                       float* __restrict__ adst1, int M) {
    __shared__ __align__(16) ushort As[2][64 * 64];    // 8 KB each: (kc*64+row)*8, kc<8
    const int tid = threadIdx.x;
    const int bm = blockIdx.x * 64;
    const int lane = tid & 63;
    const int w = tid >> 6;                            // wave = col block
    const int l16 = lane & 15, lk = lane >> 4;

    const int sakc = tid >> 6, sarow = tid & 63;       // stage slot (kc, row)
    int arow = bm + sarow; arow = arow < M ? arow : M - 1;
    const float* aptr = x + (size_t)arow * 256;
    const int sidx = (sakc * 64 + sarow) * 8;          // LDS dest (halfs)

    float4 f0, f1, f2, f3;
    auto loadA = [&](int t) {                          // 64 k: chunks sakc, sakc+4
        const float* p = aptr + t * 64;
        f0 = *(const float4*)(p + sakc * 8);
        f1 = *(const float4*)(p + sakc * 8 + 4);
        f2 = *(const float4*)(p + (sakc + 4) * 8);
        f3 = *(const float4*)(p + (sakc + 4) * 8 + 4);
    };
    auto cvtWrite = [&](int buf) {
        float fa[8] = {f0.x, f0.y, f0.z, f0.w, f1.x, f1.y, f1.z, f1.w};
        float fb[8] = {f2.x, f2.y, f2.z, f2.w, f3.x, f3.y, f3.z, f3.w};
        ushort ha[8], hb[8];
#pragma unroll
        for (int j = 0; j < 8; j++) { ha[j] = f2h(fa[j]); hb[j] = f2h(fb[j]); }
        *(uint4*)(As[buf] + sidx)              = *(uint4*)ha;
        *(uint4*)(As[buf] + sidx + 4 * 64 * 8) = *(uint4*)hb;   // kc' = sakc+4
    };

    f32x4 acc[4][4] = {};
    loadA(0);
    cvtWrite(0);
    __syncthreads();
    for (int t = 0; t < 4; t++) {
        int buf = t & 1;
        if (t + 1 < 4) loadA(t + 1);          // loads in flight over MFMA
#pragma unroll
        for (int h = 0; h < 2; h++) {         // two 32-k halves
            f16x8 a[4];
#pragma unroll
            for (int m = 0; m < 4; m++)
                a[m] = *(const f16x8*)(As[buf] + ((h * 4 + lk) * 64 + m * 16 + l16) * 8);
            f16x8 b[4];
#pragma unroll
            for (int n = 0; n < 4; n++)
                b[n] = *(const f16x8*)(WT2 +
                    ((size_t)(t * 8 + h * 4 + lk) * 256 + w * 64 + n * 16 + l16) * 8);
#pragma unroll
            for (int m = 0; m < 4; m++)
#pragma unroll
                for (int n = 0; n < 4; n++)
                    acc[m][n] = __builtin_amdgcn_mfma_f32_16x16x32_f16(a[m], b[n], acc[m][n], 0, 0, 0);
        }
        if (t + 1 < 4) cvtWrite((t + 1) & 1); // write next buf (safe: dbuf)
        __syncthreads();
    }
    // ---- epilogue: h1b (fp16) store + fused alpha (heads 2w, 2w+1) ----
    float as_v[4], ad_v[4];
#pragma unroll
    for (int n = 0; n < 4; n++) {
        int col = w * 64 + n * 16 + l16;
        as_v[n] = a_s[col];
        ad_v[n] = a_d[col];
    }
#pragma unroll
    for (int m = 0; m < 4; m++) {
#pragma unroll
        for (int j = 0; j < 4; j++) {
            int row = bm + m * 16 + lk * 4 + j;
            float ps0 = acc[m][0][j] * as_v[0] + acc[m][1][j] * as_v[1];
            float ps1 = acc[m][2][j] * as_v[2] + acc[m][3][j] * as_v[3];
            float pd0 = acc[m][0][j] * ad_v[0] + acc[m][1][j] * ad_v[1];
            float pd1 = acc[m][2][j] * ad_v[2] + acc[m][3][j] * ad_v[3];
#pragma unroll
            for (int off = 1; off < 16; off <<= 1) {
                ps0 += __shfl_xor(ps0, off);
                ps1 += __shfl_xor(ps1, off);
                pd0 += __shfl_xor(pd0, off);
                pd1 += __shfl_xor(pd1, off);
            }
            if (row < M) {
#pragma unroll
                for (int n = 0; n < 4; n++)
                    h1b[(size_t)row * 256 + w * 64 + n * 16 + l16] = f2h(acc[m][n][j]);
                if (l16 == 0) {
                    asrc1[(size_t)row * H1 + w * 2]     = ps0;
                    asrc1[(size_t)row * H1 + w * 2 + 1] = ps1;
                    adst1[(size_t)row * H1 + w * 2]     = pd0;
                    adst1[(size_t)row * H1 + w * 2 + 1] = pd1;
                }
            }
        }
    }
}

// ========== GEMM2 (MFMA fp16): [M,256]x[256,48], BK=64 ==========
// 64-row tile, 4 waves x 16 rows; A = out1 (fp16) via gload16 x2 dbuf,
// 4 K-steps; B2 (24 KB) direct from L2.  Fused alpha2 epilogue.
__global__ __launch_bounds__(256, 4) void k_gemm2_mfma(const ushort* __restrict__ o1,
                                                       const ushort* __restrict__ WT,
                                                       ushort* __restrict__ h2,
                                                       const float* __restrict__ a_s,
                                                       const float* __restrict__ a_d,
                                                       float* __restrict__ asrc2,
                                                       float* __restrict__ adst2, int M) {
    __shared__ __align__(16) ushort As[2][64 * 64];    // 8 KB each: (kc*64+row)*8
    const int tid = threadIdx.x;
    const int bm = blockIdx.x * 64;
    const int lane = tid & 63;
    const int w = tid >> 6;
    const int l16 = lane & 15, lk = lane >> 4;

    const int sakc = tid >> 6, sarow = tid & 63;
    int arow = bm + sarow; arow = arow < M ? arow : M - 1;

    auto stageA = [&](int buf, int t) {
        const ushort* p = o1 + (size_t)arow * 256 + t * 64;
        gload16(p + sakc * 8,       As[buf] + tid * 8);
        // kc' = sakc+4 lives at short-offset 4*64*8 = 2048 = (256 + tid)*8 - tid*8... i.e. (256+tid)*8
        gload16(p + (sakc + 4) * 8, As[buf] + (256 + tid) * 8);
    };

    f32x4 acc[3] = {};
    stageA(0, 0);
    __syncthreads();
    int buf = 0;
    for (int t = 0; t < 4; t++) {
        if (t + 1 < 4) stageA(buf ^ 1, t + 1);
#pragma unroll
        for (int h = 0; h < 2; h++) {
            f16x8 a2 = *(const f16x8*)(As[buf] + ((h * 4 + lk) * 64 + w * 16 + l16) * 8);
            f16x8 b2[3];
#pragma unroll
            for (int n = 0; n < 3; n++)
                b2[n] = *(const f16x8*)(WT +
                    ((size_t)(t * 8 + h * 4 + lk) * 48 + n * 16 + l16) * 8);
#pragma unroll
            for (int n = 0; n < 3; n++)
                acc[n] = __builtin_amdgcn_mfma_f32_16x16x32_f16(a2, b2[n], acc[n], 0, 0, 0);
        }
        __syncthreads();
        buf ^= 1;
    }
    // ---- epilogue: h2 (fp16, padded stride) + fused alpha2 ----
    float asv[3], adv[3];
#pragma unroll
    for (int n = 0; n < 3; n++) {
        int col = n * 16 + l16;
        asv[n] = (col < C2) ? a_s[col] : 0.f;
        adv[n] = (col < C2) ? a_d[col] : 0.f;
    }
#pragma unroll
    for (int j = 0; j < 4; j++) {
        int row = bm + w * 16 + lk * 4 + j;
        float ps = acc[0][j] * asv[0] + acc[1][j] * asv[1] + acc[2][j] * asv[2];
        float pd = acc[0][j] * adv[0] + acc[1][j] * adv[1] + acc[2][j] * adv[2];
#pragma unroll
        for (int off = 1; off < 16; off <<= 1) {
            ps += __shfl_xor(ps, off);
            pd += __shfl_xor(pd, off);
        }
        if (row < M) {
#pragma unroll
            for (int n = 0; n < 3; n++)
                h2[(size_t)row * S2 + n * 16 + l16] = f2h(acc[n][j]);
            if (l16 == 0) { asrc2[row] = ps; adst2[row] = pd; }
        }
    }
}

// ======== layer-1 aggregation: half-wave per edge, 4-deep unrolled ========
__global__ __launch_bounds__(256) void k_gat_aggr1(const int* __restrict__ row_off,
                                                   const int* __restrict__ csr_src,
                                                   const float* __restrict__ asrc,
                                                   const float* __restrict__ adst,
                                                   const ushort* __restrict__ h1b,
                                                   const float* __restrict__ bias,
                                                   ushort* __restrict__ o1) {
    int wid = (blockIdx.x * 256 + threadIdx.x) >> 6;   // node id
    if (wid >= Nn) return;
    int lane = threadIdx.x & 63;
    int half = lane >> 5, l32 = lane & 31;
    int head = l32 >> 2;                 // 4 lanes per head, 8 ch each
    int c0 = l32 * 8;
    int beg = row_off[wid], end = row_off[wid + 1];
    float ad = adst[(size_t)wid * H1 + head];
    float acc[8] = {};
    float sump = 0.f;
    int i = beg + half;
    for (; i + 6 < end; i += 8) {        // 4 edges per half per iter
        int s0 = csr_src[i],     s1 = csr_src[i + 2];
        int s2 = csr_src[i + 4], s3 = csr_src[i + 6];
        float a0 = asrc[(size_t)s0 * H1 + head], a1 = asrc[(size_t)s1 * H1 + head];
        float a2 = asrc[(size_t)s2 * H1 + head], a3 = asrc[(size_t)s3 * H1 + head];
        ushort4 w0 = *(const ushort4*)(h1b + (size_t)s0 * HC1 + c0);
        ushort4 w0b = *(const ushort4*)(h1b + (size_t)s0 * HC1 + c0 + 4);
        ushort4 w1 = *(const ushort4*)(h1b + (size_t)s1 * HC1 + c0);
        ushort4 w1b = *(const ushort4*)(h1b + (size_t)s1 * HC1 + c0 + 4);
        ushort4 w2 = *(const ushort4*)(h1b + (size_t)s2 * HC1 + c0);
        ushort4 w2b = *(const ushort4*)(h1b + (size_t)s2 * HC1 + c0 + 4);
        ushort4 w3 = *(const ushort4*)(h1b + (size_t)s3 * HC1 + c0);
        ushort4 w3b = *(const ushort4*)(h1b + (size_t)s3 * HC1 + c0 + 4);
        float l0 = a0 + ad; l0 = l0 > 0.f ? l0 : SLOPE * l0;
        float l1 = a1 + ad; l1 = l1 > 0.f ? l1 : SLOPE * l1;
        float l2 = a2 + ad; l2 = l2 > 0.f ? l2 : SLOPE * l2;
        float l3 = a3 + ad; l3 = l3 > 0.f ? l3 : SLOPE * l3;
        float p0 = __expf(l0), p1 = __expf(l1), p2 = __expf(l2), p3 = __expf(l3);
        sump += (p0 + p1) + (p2 + p3);
        ushort v0[8] = {w0.x, w0.y, w0.z, w0.w, w0b.x, w0b.y, w0b.z, w0b.w};
        ushort v1[8] = {w1.x, w1.y, w1.z, w1.w, w1b.x, w1b.y, w1b.z, w1b.w};
        ushort v2[8] = {w2.x, w2.y, w2.z, w2.w, w2b.x, w2b.y, w2b.z, w2b.w};
        ushort v3[8] = {w3.x, w3.y, w3.z, w3.w, w3b.x, w3b.y, w3b.z, w3b.w};
#pragma unroll
        for (int j = 0; j < 8; j++)
            acc[j] += (p0 * h2f(v0[j]) + p1 * h2f(v1[j])) +
                      (p2 * h2f(v2[j]) + p3 * h2f(v3[j]));
    }
    for (; i < end; i += 2) {
        int s = csr_src[i];
        float a = asrc[(size_t)s * H1 + head];
        ushort4 wv = *(const ushort4*)(h1b + (size_t)s * HC1 + c0);
        ushort4 wb = *(const ushort4*)(h1b + (size_t)s * HC1 + c0 + 4);
        float l = a + ad; l = l > 0.f ? l : SLOPE * l;
        float p = __expf(l);
        sump += p;
        ushort v[8] = {wv.x, wv.y, wv.z, wv.w, wb.x, wb.y, wb.z, wb.w};
#pragma unroll
        for (int j = 0; j < 8; j++) acc[j] += p * h2f(v[j]);
    }
    // merge the two half-waves
    sump += __shfl_xor(sump, 32);
#pragma unroll
    for (int j = 0; j < 8; j++) acc[j] += __shfl_xor(acc[j], 32);
    if (half) return;
    float inv = 1.f / sump;              // degree >= 1 (self-loop)
    float4 b0 = *(const float4*)(bias + c0);
    float4 b1 = *(const float4*)(bias + c0 + 4);
    float bb[8] = {b0.x, b0.y, b0.z, b0.w, b1.x, b1.y, b1.z, b1.w};
    ushort hh[8];
#pragma unroll
    for (int j = 0; j < 8; j++) {
        float r = acc[j] * inv + bb[j];
        r = r > 0.f ? r : __expf(r) - 1.f;         // fused ELU
        hh[j] = f2h(r);
    }
    *(uint4*)(o1 + (size_t)wid * HC1 + c0) = *(uint4*)hh;
}

// ====== layer-2 aggregation: 2 nodes/wave (half-wave/node, 2 ch/lane) ======
__global__ __launch_bounds__(256) void k_gat_aggr2(const int* __restrict__ row_off,
                                                   const int* __restrict__ csr_src,
                                                   const float* __restrict__ asrc,
                                                   const float* __restrict__ adst,
                                                   const ushort* __restrict__ h2,
                                                   const float* __restrict__ bias,
                                                   float* __restrict__ out) {
    int gw = (blockIdx.x * 256 + threadIdx.x) >> 6;    // wave id
    int lane = threadIdx.x & 63;
    int half = lane >> 5, l32 = lane & 31;
    int wid = gw * 2 + half;                           // node id (per half-wave)
    if (wid >= Nn) return;
    int c = l32 * 2;                                   // 2 channels per lane
    int beg = row_off[wid], end = row_off[wid + 1];
    float ad = adst[wid];
    float acc0 = 0.f, acc1 = 0.f, sump = 0.f;
    int i = beg;
    for (; i + 3 < end; i += 4) {
        int s0 = csr_src[i], s1 = csr_src[i + 1], s2 = csr_src[i + 2], s3 = csr_src[i + 3];
        float a0 = asrc[s0], a1 = asrc[s1], a2 = asrc[s2], a3 = asrc[s3];
        uint u0 = *(const uint*)(h2 + (size_t)s0 * S2 + c);
        uint u1 = *(const uint*)(h2 + (size_t)s1 * S2 + c);
        uint u2 = *(const uint*)(h2 + (size_t)s2 * S2 + c);
        uint u3 = *(const uint*)(h2 + (size_t)s3 * S2 + c);
        float l0 = a0 + ad; l0 = l0 > 0.f ? l0 : SLOPE * l0;
        float l1 = a1 + ad; l1 = l1 > 0.f ? l1 : SLOPE * l1;
        float l2 = a2 + ad; l2 = l2 > 0.f ? l2 : SLOPE * l2;
        float l3 = a3 + ad; l3 = l3 > 0.f ? l3 : SLOPE * l3;
        float p0 = __expf(l0), p1 = __expf(l1), p2 = __expf(l2), p3 = __expf(l3);
        sump += (p0 + p1) + (p2 + p3);
        acc0 += p0 * h2f((ushort)(u0 & 0xffff)) + p1 * h2f((ushort)(u1 & 0xffff)) +
                p2 * h2f((ushort)(u2 & 0xffff)) + p3 * h2f((ushort)(u3 & 0xffff));
        acc1 += p0 * h2f((ushort)(u0 >> 16)) + p1 * h2f((ushort)(u1 >> 16)) +
                p2 * h2f((ushort)(u2 >> 16)) + p3 * h2f((ushort)(u3 >> 16));
    }
    for (; i < end; i++) {
        int s = csr_src[i];
        float l = asrc[s] + ad;
        l = l > 0.f ? l : SLOPE * l;
        float pe = __expf(l);
        sump += pe;
        uint u = *(const uint*)(h2 + (size_t)s * S2 + c);
        acc0 += pe * h2f((ushort)(u & 0xffff));
        acc1 += pe * h2f((ushort)(u >> 16));
    }
    if (c < C2) {
        float inv = 1.f / sump;
        float2 r;
        r.x = acc0 * inv + bias[c];
        r.y = acc1 * inv + bias[c + 1];
        *(float2*)(out + (size_t)wid * C2 + c) = r;
    }
}

// ---------------- launch ----------------
extern "C" void kernel_launch(void* const* d_in, const int* in_sizes, int n_in,
                              void* d_out, int out_size, void* d_ws, size_t ws_size,
                              hipStream_t stream) {
    const float* x   = (const float*)d_in[0];
    const int*   ei  = (const int*)d_in[1];
    const float* w1  = (const float*)d_in[2];
    const float* as1 = (const float*)d_in[3];
    const float* ad1 = (const float*)d_in[4];
    const float* b1  = (const float*)d_in[5];
    const float* w2  = (const float*)d_in[6];
    const float* as2 = (const float*)d_in[7];
    const float* ad2 = (const float*)d_in[8];
    const float* b2  = (const float*)d_in[9];
    float* outp = (float*)d_out;

    const int* srcA = ei;
    const int* dstA = ei + Ee;

    char* W = (char*)d_ws;
    size_t o = 0;
    auto allocB = [&](size_t bytes) { void* p = W + o; o += (bytes + 255) & ~(size_t)255; return p; };

    ushort* o1    = (ushort*)allocB((size_t)Nn * HC1 * 2);   // 25.6 MB (fp16 out1)
    ushort* wt2   = (ushort*)allocB((size_t)256 * 256 * 2);  // packed W1 fp16 (131 KB)
    ushort* wt2b  = (ushort*)allocB((size_t)256 * 48 * 2);   // packed W2 fp16 (24 KB)
    ushort* h1b   = (ushort*)allocB((size_t)Nn * HC1 * 2);   // 25.6 MB (fp16)
    ushort* h2    = (ushort*)allocB((size_t)Nn * S2 * 2);    // 6.4 MB (fp16, padded)
    float*  asrc1 = (float*)allocB((size_t)Nn * H1 * 4);
    float*  adst1 = (float*)allocB((size_t)Nn * H1 * 4);
    float*  asrc2 = (float*)allocB((size_t)Nn * 4);
    float*  adst2 = (float*)allocB((size_t)Nn * 4);
    int* counts   = (int*)allocB((size_t)Nn * 4);
    int* exsc     = (int*)allocB((size_t)Nn * 4);
    int* bsum     = (int*)allocB(256 * 4);
    int* row_off  = (int*)allocB((size_t)(Nn + 1) * 4);
    int* cursor   = (int*)allocB((size_t)Nn * 4);
    int* csr_src  = (int*)allocB((size_t)ETot * 4);

    // ---- prep (weight packs + degree histogram, one dispatch) ----
    hipMemsetAsync(counts, 0, (size_t)Nn * sizeof(int), stream);
    k_prep<<<(ETot + 255) / 256, 256, 0, stream>>>(w1, wt2, w2, wt2b, dstA, counts);

    // ---- CSR build (graph shared by both layers) ----
    k_scan_block<<<NB_SCAN, 256, 0, stream>>>(counts, exsc, bsum);
    k_finalize2<<<NB_SCAN, 256, 0, stream>>>(exsc, bsum, row_off, cursor);
    k_scatter<<<(ETot + 255) / 256, 256, 0, stream>>>(srcA, dstA, cursor, csr_src);

    // ---- layer 1 (alpha fused into GEMM epilogue; x read f32-direct) ----
    k_gemm1_mfma<<<(Nn + 63) / 64, 256, 0, stream>>>(
        x, wt2, h1b, as1, ad1, asrc1, adst1, Nn);
    k_gat_aggr1<<<(int)(((size_t)Nn * 64 + 255) / 256), 256, 0, stream>>>(
        row_off, csr_src, asrc1, adst1, h1b, b1, o1);

    // ---- layer 2 (alpha fused into GEMM epilogue) ----
    k_gemm2_mfma<<<(Nn + 63) / 64, 256, 0, stream>>>(
        o1, wt2b, h2, as2, ad2, asrc2, adst2, Nn);
    int waves2 = (Nn + 1) / 2;
    k_gat_aggr2<<<(int)(((size_t)waves2 * 64 + 255) / 256), 256, 0, stream>>>(
        row_off, csr_src, asrc2, adst2, h2, b2, outp);
}